// Round 3
// baseline (370.199 us; speedup 1.0000x reference)
//
#include <hip/hip_runtime.h>

typedef __attribute__((ext_vector_type(8))) __bf16 bf16x8;
typedef __attribute__((ext_vector_type(8))) unsigned short ushort8;
typedef __attribute__((ext_vector_type(4))) float f32x4;

constexpr int B_ = 2, C_ = 32, NN = 64;
constexpr int PK = 3375;              // 15^3
constexpr int K_TOT = C_ * PK;        // 108000
constexpr int F_TOT = 1024;
constexpr int M_TOT = 128;            // B*N
constexpr int KSTEPS = K_TOT / 32;    // 3375 (exact)

__device__ __forceinline__ unsigned short f2bf(float f) {
    unsigned int b = __builtin_bit_cast(unsigned int, f);
    b += 0x7FFFu + ((b >> 16) & 1u);      // round-to-nearest-even
    return (unsigned short)(b >> 16);
}

// ---------------- kernel 1: patch gather -> bf16 A[128][108000] ----------------
__global__ void extract_kernel(const float* __restrict__ x,
                               const int* __restrict__ cent,
                               unsigned short* __restrict__ A) {
    int m = blockIdx.x;            // 0..127  (b*64+n)
    int c = blockIdx.y;            // 0..31
    int b = m >> 6, n = m & 63;
    int cx = cent[(b * NN + n) * 3 + 0];
    int cy = cent[(b * NN + n) * 3 + 1];
    int cz = cent[(b * NN + n) * 3 + 2];
    int sx = max(cx - 7, 0), ex = min(cx + 8, 96);
    int sy = max(cy - 7, 0), ey = min(cy + 8, 96);
    int sz = max(cz - 7, 0), ez = min(cz + 8, 96);
    const float* xb = x + (size_t)(b * C_ + c) * (96 * 96 * 96);
    unsigned short* Arow = A + (size_t)m * K_TOT + (size_t)c * PK;
    for (int k = threadIdx.x; k < PK; k += blockDim.x) {
        int iz = k % 15;
        int t  = k / 15;
        int iy = t % 15;
        int ix = t / 15;
        int hx = sx + ix, wy = sy + iy, dz = sz + iz;
        float v = 0.0f;
        if (hx < ex && wy < ey && dz < ez)
            v = xb[(hx * 96 + wy) * 96 + dz];
        Arow[k] = f2bf(v);
    }
}

// ---------------- kernel 1b: W fp32 [k][f] -> bf16 tiled Wt[f/64][k/32][f%64][k%32] --
// Each block owns one 32-row k-slab; reads full 4KB rows coalesced+sequential,
// each thread owns one f column and writes its 64B (32 bf16) chunk contiguously.
// GEMM block (fx,s) then reads a single fully-sequential byte range.
__global__ __launch_bounds__(1024) void wconvert_kernel(const float* __restrict__ W,
                                                        unsigned short* __restrict__ Wt) {
    int kblk = blockIdx.x;             // 0..KSTEPS-1
    int t = (int)threadIdx.x;          // 0..1023 : f column
    const float* src = W + (size_t)kblk * 32 * F_TOT + t;
    float v[32];
#pragma unroll
    for (int k = 0; k < 32; ++k)
        v[k] = __builtin_nontemporal_load(src + (size_t)k * F_TOT);
    unsigned int pk[16];
#pragma unroll
    for (int j = 0; j < 16; ++j)
        pk[j] = (unsigned)f2bf(v[2 * j]) | ((unsigned)f2bf(v[2 * j + 1]) << 16);
    // dest byte offset: ((t/64)*KSTEPS + kblk)*4096 + (t%64)*64
    f32x4* dst = (f32x4*)(Wt + ((size_t)(t >> 6) * KSTEPS + kblk) * 2048
                             + (size_t)(t & 63) * 32);
    const f32x4* s4 = (const f32x4*)pk;
#pragma unroll
    for (int j = 0; j < 4; ++j) dst[j] = s4[j];
}

// ---------------- kernel 2: split-K GEMM, sequential-stream W, reg prefetch ------
__global__ __launch_bounds__(256) void gemm_kernel(const unsigned short* __restrict__ A,
                                                   const unsigned short* __restrict__ Wt,
                                                   float* __restrict__ partial,
                                                   int CS) {
    int fx = blockIdx.x;                       // 0..15 : 64-col F tile
    int s  = blockIdx.y;                       // K-chunk
    int st0 = s * CS;
    int st1 = min(st0 + CS, KSTEPS);

    int tid  = (int)threadIdx.x;
    int wave = tid >> 6, lane = tid & 63;
    int fr = lane & 15, lgrp = lane >> 4;
    int f = fx * 64 + wave * 16 + fr;          // this lane's f column

    f32x4 acc[8];
#pragma unroll
    for (int i = 0; i < 8; ++i) acc[i] = (f32x4)(0.0f);

    // B: within step-chunk [64f][32k], lane reads 16B at f_local*64 + lgrp*16
    const unsigned short* Bp = Wt + ((size_t)fx * KSTEPS + st0) * 2048
                                  + (size_t)(wave * 16 + fr) * 32 + lgrp * 8;
    const unsigned short* Ap = A + (size_t)fr * K_TOT + st0 * 32 + lgrp * 8;

    bf16x8 bfrag = *reinterpret_cast<const bf16x8*>(Bp);
    bf16x8 afrag[8];
#pragma unroll
    for (int mt = 0; mt < 8; ++mt)
        afrag[mt] = *reinterpret_cast<const bf16x8*>(Ap + (size_t)(mt * 16) * K_TOT);

    for (int st = st0; st < st1 - 1; ++st) {
        // prefetch next step into fresh registers
        bf16x8 bnext = *reinterpret_cast<const bf16x8*>(Bp + 2048);
        bf16x8 anext[8];
#pragma unroll
        for (int mt = 0; mt < 8; ++mt)
            anext[mt] = *reinterpret_cast<const bf16x8*>(Ap + 32 + (size_t)(mt * 16) * K_TOT);
        // compute current
#pragma unroll
        for (int mt = 0; mt < 8; ++mt)
            acc[mt] = __builtin_amdgcn_mfma_f32_16x16x32_bf16(afrag[mt], bfrag, acc[mt], 0, 0, 0);
        bfrag = bnext;
#pragma unroll
        for (int mt = 0; mt < 8; ++mt) afrag[mt] = anext[mt];
        Bp += 2048;
        Ap += 32;
    }
    // epilogue step
#pragma unroll
    for (int mt = 0; mt < 8; ++mt)
        acc[mt] = __builtin_amdgcn_mfma_f32_16x16x32_bf16(afrag[mt], bfrag, acc[mt], 0, 0, 0);

    // --- write partials: D row = lgrp*4 + r, col = fr (m89-verified mapping) ---
    float* pout = partial + (size_t)s * (M_TOT * F_TOT);
#pragma unroll
    for (int mt = 0; mt < 8; ++mt) {
        int mbase = mt * 16 + lgrp * 4;
#pragma unroll
        for (int r = 0; r < 4; ++r)
            pout[(size_t)(mbase + r) * F_TOT + f] = acc[mt][r];
    }
}

// ---------------- kernel 3: split-K reduce + bias ----------------
__global__ void reduce_kernel(const float* __restrict__ partial,
                              const float* __restrict__ bias,
                              float* __restrict__ out, int S) {
    int i = blockIdx.x * blockDim.x + threadIdx.x;
    if (i >= M_TOT * F_TOT) return;
    float a = bias[i & (F_TOT - 1)];
    for (int s = 0; s < S; ++s)
        a += partial[(size_t)s * (M_TOT * F_TOT) + i];
    out[i] = a;
}

extern "C" void kernel_launch(void* const* d_in, const int* in_sizes, int n_in,
                              void* d_out, int out_size, void* d_ws, size_t ws_size,
                              hipStream_t stream) {
    const float* x    = (const float*)d_in[0];
    const int*   cent = (const int*)d_in[1];
    const float* W    = (const float*)d_in[2];
    const float* bias = (const float*)d_in[3];
    float* out = (float*)d_out;

    unsigned short* A = (unsigned short*)d_ws;
    size_t A_bytes  = (size_t)M_TOT * K_TOT * 2;                  // 27,648,000
    unsigned short* Wt = (unsigned short*)((char*)d_ws + A_bytes);
    size_t Wt_bytes = (size_t)16 * KSTEPS * 4096;                 // 221,184,000
    float* partial = (float*)((char*)d_ws + A_bytes + Wt_bytes);

    size_t used = A_bytes + Wt_bytes;
    size_t avail = ws_size > used ? ws_size - used : 0;
    int S = (int)(avail / ((size_t)M_TOT * F_TOT * 4));
    if (S > 64) S = 64;
    if (S < 1)  S = 1;
    int CS = (KSTEPS + S - 1) / S;
    S = (KSTEPS + CS - 1) / CS;   // drop empty chunks

    extract_kernel<<<dim3(M_TOT, C_), 256, 0, stream>>>(x, cent, A);
    wconvert_kernel<<<dim3(KSTEPS), 1024, 0, stream>>>(W, Wt);
    gemm_kernel<<<dim3(16, S), 256, 0, stream>>>(A, Wt, partial, CS);
    reduce_kernel<<<dim3((M_TOT * F_TOT) / 256), 256, 0, stream>>>(partial, bias, out, S);
}

// Round 4
// 194.418 us; speedup vs baseline: 1.9041x; 1.9041x over previous
//
#include <hip/hip_runtime.h>

typedef __attribute__((ext_vector_type(8))) __bf16 bf16x8;
typedef __attribute__((ext_vector_type(8))) unsigned short ushort8;
typedef __attribute__((ext_vector_type(4))) float f32x4;

constexpr int B_ = 2, C_ = 32, NN = 64;
constexpr int PK = 3375;              // 15^3
constexpr int K_TOT = C_ * PK;        // 108000
constexpr int F_TOT = 1024;
constexpr int M_TOT = 128;            // B*N
constexpr int KSTEPS = K_TOT / 32;    // 3375 (exact)

__device__ __forceinline__ unsigned short f2bf(float f) {
    unsigned int b = __builtin_bit_cast(unsigned int, f);
    b += 0x7FFFu + ((b >> 16) & 1u);      // round-to-nearest-even
    return (unsigned short)(b >> 16);
}

// async 16B global -> LDS (wave-uniform LDS base + implicit lane*16 spread)
__device__ __forceinline__ void async_copy16(void* lds, const void* g) {
    __builtin_amdgcn_global_load_lds(
        (const __attribute__((address_space(1))) unsigned int*)g,
        (__attribute__((address_space(3))) unsigned int*)lds, 16, 0, 0);
}

// ---------------- kernel 1: patch gather -> bf16 A in MFMA-FRAGMENT order --------
// Af layout: [step 0..3374][mt 0..7][lane 0..63][e 0..7] bf16, where the value at
// (st, mt, lane=lgrp*16+fr, e) = A[m = fr + mt*16][k = st*32 + lgrp*8 + e].
// GEMM then reads each A-fragment as ONE dwordx4, wave-contiguous 1KB.
__global__ void extract_kernel(const float* __restrict__ x,
                               const int* __restrict__ cent,
                               unsigned short* __restrict__ Af) {
    int m = blockIdx.x;            // 0..127  (b*64+n)
    int c = blockIdx.y;            // 0..31
    int b = m >> 6, n = m & 63;
    int mt = m >> 4, fr = m & 15;
    int cx = cent[(b * NN + n) * 3 + 0];
    int cy = cent[(b * NN + n) * 3 + 1];
    int cz = cent[(b * NN + n) * 3 + 2];
    int sx = max(cx - 7, 0), ex = min(cx + 8, 96);
    int sy = max(cy - 7, 0), ey = min(cy + 8, 96);
    int sz = max(cz - 7, 0), ez = min(cz + 8, 96);
    const float* xb = x + (size_t)(b * C_ + c) * (96 * 96 * 96);
    for (int k = threadIdx.x; k < PK; k += blockDim.x) {
        int iz = k % 15;
        int t  = k / 15;
        int iy = t % 15;
        int ix = t / 15;
        int hx = sx + ix, wy = sy + iy, dz = sz + iz;
        float v = 0.0f;
        if (hx < ex && wy < ey && dz < ez)
            v = xb[(hx * 96 + wy) * 96 + dz];
        int K  = c * PK + k;
        int st = K >> 5, kr = K & 31;
        int lg = kr >> 3, e = kr & 7;
        size_t off = (size_t)st * 4096 + (size_t)mt * 512 + (size_t)(lg * 16 + fr) * 8 + e;
        Af[off] = f2bf(v);
    }
}

// ---------------- kernel 2: split-K GEMM ------------------------------------------
// W fp32 staged to LDS via global_load_lds (read ONCE from HBM, no VGPR cost),
// converted to bf16 on ds_read. A-fragments read direct from global (L3-resident,
// fragment-ordered, 1 dwordx4 each). Tile: M=128 x F=256 per block, k-step 32.
// 4 waves; wave owns 64 f-cols; per wave-step: 8 A-loads, 32 ds_read_b32, 32 MFMA.
__global__ __launch_bounds__(256, 2) void gemm_kernel(const unsigned short* __restrict__ Af,
                                                      const float* __restrict__ W,
                                                      float* __restrict__ partial,
                                                      int CS) {
    __shared__ float wlds[32 * 256];           // 32 KB: [k 0..31][f 0..255] fp32
    int fx = blockIdx.x;                       // 0..3 : 256-col F tile
    int s  = blockIdx.y;                       // K-chunk
    int st0 = s * CS;
    int st1 = min(st0 + CS, KSTEPS);
    int f0  = fx * 256;

    int tid  = (int)threadIdx.x;
    int wave = tid >> 6, lane = tid & 63;
    int fr = lane & 15, lgrp = lane >> 4;

    f32x4 acc[8][4];                           // [mt][ft]
#pragma unroll
    for (int i = 0; i < 8; ++i)
#pragma unroll
        for (int j = 0; j < 4; ++j) acc[i][j] = (f32x4)(0.0f);

    for (int st = st0; st < st1; ++st) {
        int k0 = st << 5;
        // --- stage W[k0..k0+31][f0..f0+255] fp32 -> LDS, fully async ---
        // round r, wave w: row k = r*4 + w, lane covers 16B at f = lane*4
        {
            const float* wsrc = W + (size_t)k0 * F_TOT + f0 + lane * 4;
#pragma unroll
            for (int r = 0; r < 8; ++r) {
                int krow = r * 4 + wave;
                async_copy16((char*)wlds + (size_t)krow * 1024,
                             wsrc + (size_t)krow * F_TOT);
            }
        }
        __syncthreads();   // compiler emits vmcnt(0) drain here

        // --- A fragments: one dwordx4 each, wave reads 1KB contiguous ---
        const unsigned short* Ap = Af + (size_t)st * 4096 + (size_t)lane * 8;
        bf16x8 afrag[8];
#pragma unroll
        for (int mt = 0; mt < 8; ++mt)
            afrag[mt] = *reinterpret_cast<const bf16x8*>(Ap + (size_t)mt * 512);

        // --- per f-tile: read W frag from LDS, cvt to bf16, 8 MFMAs ---
#pragma unroll
        for (int ft = 0; ft < 4; ++ft) {
            int fl = wave * 64 + ft * 16 + fr;
            float wv[8];
#pragma unroll
            for (int j = 0; j < 8; ++j)
                wv[j] = wlds[(lgrp * 8 + j) * 256 + fl];
            ushort8 bt;
#pragma unroll
            for (int j = 0; j < 8; ++j)
                bt[j] = f2bf(wv[j]);
            bf16x8 bfrag = __builtin_bit_cast(bf16x8, bt);
#pragma unroll
            for (int mt = 0; mt < 8; ++mt)
                acc[mt][ft] = __builtin_amdgcn_mfma_f32_16x16x32_bf16(afrag[mt], bfrag, acc[mt][ft], 0, 0, 0);
        }
        __syncthreads();   // protect wlds before next-step overwrite
    }

    // --- write partials: D row = lgrp*4 + r, col = fr (m89-verified mapping) ---
    float* pout = partial + (size_t)s * (M_TOT * F_TOT);
#pragma unroll
    for (int mt = 0; mt < 8; ++mt) {
        int mbase = mt * 16 + lgrp * 4;
#pragma unroll
        for (int ft = 0; ft < 4; ++ft) {
            int f = f0 + wave * 64 + ft * 16 + fr;
#pragma unroll
            for (int r = 0; r < 4; ++r)
                pout[(size_t)(mbase + r) * F_TOT + f] = acc[mt][ft][r];
        }
    }
}

// ---------------- kernel 3: split-K reduce + bias ----------------
__global__ void reduce_kernel(const float* __restrict__ partial,
                              const float* __restrict__ bias,
                              float* __restrict__ out, int S) {
    int i = blockIdx.x * blockDim.x + threadIdx.x;
    if (i >= M_TOT * F_TOT) return;
    float a = bias[i & (F_TOT - 1)];
    for (int s = 0; s < S; ++s)
        a += partial[(size_t)s * (M_TOT * F_TOT) + i];
    out[i] = a;
}

extern "C" void kernel_launch(void* const* d_in, const int* in_sizes, int n_in,
                              void* d_out, int out_size, void* d_ws, size_t ws_size,
                              hipStream_t stream) {
    const float* x    = (const float*)d_in[0];
    const int*   cent = (const int*)d_in[1];
    const float* W    = (const float*)d_in[2];
    const float* bias = (const float*)d_in[3];
    float* out = (float*)d_out;

    unsigned short* Af = (unsigned short*)d_ws;
    size_t Af_bytes = (size_t)KSTEPS * 4096 * 2;                 // 27,648,000
    float* partial = (float*)((char*)d_ws + Af_bytes);

    size_t avail = ws_size > Af_bytes ? ws_size - Af_bytes : 0;
    int S = (int)(avail / ((size_t)M_TOT * F_TOT * 4));
    if (S > 125) S = 125;                 // 3375 = 27 * 125 -> CS=27 exact
    if (S < 1)   S = 1;
    int CS = (KSTEPS + S - 1) / S;
    S = (KSTEPS + CS - 1) / CS;           // drop empty chunks

    extract_kernel<<<dim3(M_TOT, C_), 256, 0, stream>>>(x, cent, Af);
    gemm_kernel<<<dim3(4, S), 256, 0, stream>>>(Af, W, partial, CS);
    reduce_kernel<<<dim3((M_TOT * F_TOT) / 256), 256, 0, stream>>>(partial, bias, out, S);
}

// Round 5
// 173.583 us; speedup vs baseline: 2.1327x; 1.1200x over previous
//
#include <hip/hip_runtime.h>

typedef __attribute__((ext_vector_type(8))) __bf16 bf16x8;
typedef __attribute__((ext_vector_type(8))) unsigned short ushort8;
typedef __attribute__((ext_vector_type(4))) float f32x4;

constexpr int B_ = 2, C_ = 32, NN = 64;
constexpr int PK = 3375;              // 15^3
constexpr int K_TOT = C_ * PK;        // 108000
constexpr int F_TOT = 1024;
constexpr int M_TOT = 128;            // B*N
constexpr int KSTEPS = K_TOT / 32;    // 3375 (exact)

__device__ __forceinline__ unsigned short f2bf(float f) {
    unsigned int b = __builtin_bit_cast(unsigned int, f);
    b += 0x7FFFu + ((b >> 16) & 1u);      // round-to-nearest-even
    return (unsigned short)(b >> 16);
}

// async 16B global -> LDS (wave-uniform LDS base + implicit lane*16 spread)
__device__ __forceinline__ void async_copy16(void* lds, const void* g) {
    __builtin_amdgcn_global_load_lds(
        (const __attribute__((address_space(1))) unsigned int*)g,
        (__attribute__((address_space(3))) unsigned int*)lds, 16, 0, 0);
}

// ---------------- kernel 1: patch gather -> bf16 A in MFMA-FRAGMENT order --------
// Af layout: [step 0..3374][mt 0..7][lane 0..63][e 0..7] bf16, value at
// (st, mt, lane=lgrp*16+fr, e) = A[m = fr + mt*16][k = st*32 + lgrp*8 + e].
__global__ void extract_kernel(const float* __restrict__ x,
                               const int* __restrict__ cent,
                               unsigned short* __restrict__ Af) {
    int m = blockIdx.x;            // 0..127  (b*64+n)
    int c = blockIdx.y;            // 0..31
    int b = m >> 6, n = m & 63;
    int mt = m >> 4, fr = m & 15;
    int cx = cent[(b * NN + n) * 3 + 0];
    int cy = cent[(b * NN + n) * 3 + 1];
    int cz = cent[(b * NN + n) * 3 + 2];
    int sx = max(cx - 7, 0), ex = min(cx + 8, 96);
    int sy = max(cy - 7, 0), ey = min(cy + 8, 96);
    int sz = max(cz - 7, 0), ez = min(cz + 8, 96);
    const float* xb = x + (size_t)(b * C_ + c) * (96 * 96 * 96);
    for (int k = threadIdx.x; k < PK; k += blockDim.x) {
        int iz = k % 15;
        int t  = k / 15;
        int iy = t % 15;
        int ix = t / 15;
        int hx = sx + ix, wy = sy + iy, dz = sz + iz;
        float v = 0.0f;
        if (hx < ex && wy < ey && dz < ez)
            v = xb[(hx * 96 + wy) * 96 + dz];
        int K  = c * PK + k;
        int st = K >> 5, kr = K & 31;
        int lg = kr >> 3, e = kr & 7;
        size_t off = (size_t)st * 4096 + (size_t)mt * 512 + (size_t)(lg * 16 + fr) * 8 + e;
        Af[off] = f2bf(v);
    }
}

// ---------------- kernel 2: split-K GEMM, dbuf LDS + counted vmcnt ---------------
// Tile: M=128 x F=128 per block, k-step 32, 4 waves (wave owns 32 f-cols).
// W fp32 staged via global_load_lds into wlds[2][32][128] (16KB/step); next step
// staged BEFORE compute, drained with vmcnt(4) (4 load_lds per wave stay in
// flight across the barrier -> memory pipe never idles). A-frags: 1 dwordx4 each,
// L2-resident via XCD swizzle (all 8 fx-blocks of a chunk on one XCD).
__global__ __launch_bounds__(256, 2) void gemm_kernel(const unsigned short* __restrict__ Af,
                                                      const float* __restrict__ W,
                                                      float* __restrict__ partial,
                                                      int CS) {
    __shared__ float wlds[2][32][128];         // 2 x 16 KB
    int fx, s;
    if (gridDim.y == 64) {                     // bijective XCD swizzle (512 = 8*64)
        int id = blockIdx.y * 8 + blockIdx.x;
        int xcd = id & 7, q = id >> 3;
        s  = xcd * 8 + (q & 7);                // chunk s pinned to XCD s>>3
        fx = q >> 3;
    } else { fx = blockIdx.x; s = blockIdx.y; }
    int st0 = s * CS;
    int st1 = min(st0 + CS, KSTEPS);
    int f0  = fx * 128;

    int tid  = (int)threadIdx.x;
    int wave = tid >> 6, lane = tid & 63;
    int fr = lane & 15, lgrp = lane >> 4;
    int row2 = lane >> 5;                      // 0/1: which of the round's 2 rows
    int col4 = (lane & 31) * 4;                // 16B group within 512B row

    f32x4 acc[8][2];
#pragma unroll
    for (int i = 0; i < 8; ++i)
#pragma unroll
        for (int j = 0; j < 2; ++j) acc[i][j] = (f32x4)(0.0f);

    // stage one 32x128 fp32 W tile: 4 rounds/wave, 1KB (=2 rows) per round
    auto STAGE = [&](int buf, int st) {
        const float* wsrc = W + ((size_t)st * 32 + row2) * F_TOT + f0 + col4;
#pragma unroll
        for (int r = 0; r < 4; ++r) {
            int rowbase = (r * 4 + wave) * 2;
            async_copy16(&wlds[buf][rowbase][0], wsrc + (size_t)rowbase * F_TOT);
        }
    };
    auto ALOAD = [&](int st, bf16x8* afrag) {
        const unsigned short* Ap = Af + (size_t)st * 4096 + (size_t)lane * 8;
#pragma unroll
        for (int mt = 0; mt < 8; ++mt)
            afrag[mt] = *reinterpret_cast<const bf16x8*>(Ap + (size_t)mt * 512);
    };
    auto COMPUTE = [&](int buf, bf16x8* afrag) {
#pragma unroll
        for (int ft = 0; ft < 2; ++ft) {
            int fl = wave * 32 + ft * 16 + fr;
            float wv[8];
#pragma unroll
            for (int j = 0; j < 8; ++j)
                wv[j] = wlds[buf][lgrp * 8 + j][fl];
            ushort8 bt;
#pragma unroll
            for (int j = 0; j < 8; ++j)
                bt[j] = f2bf(wv[j]);
            bf16x8 bfrag = __builtin_bit_cast(bf16x8, bt);
#pragma unroll
            for (int mt = 0; mt < 8; ++mt)
                acc[mt][ft] = __builtin_amdgcn_mfma_f32_16x16x32_bf16(afrag[mt], bfrag, acc[mt][ft], 0, 0, 0);
        }
    };

    bf16x8 afrag[8];
    int cur = 0;
    STAGE(0, st0);
    for (int t = st0; t < st1 - 1; ++t) {
        ALOAD(t, afrag);
        STAGE(cur ^ 1, t + 1);
        asm volatile("s_waitcnt vmcnt(4)" ::: "memory");  // own stage(t)+A(t) done; stage(t+1) in flight
        __builtin_amdgcn_s_barrier();
        COMPUTE(cur, afrag);
        __builtin_amdgcn_s_barrier();
        cur ^= 1;
    }
    ALOAD(st1 - 1, afrag);
    asm volatile("s_waitcnt vmcnt(0)" ::: "memory");
    __builtin_amdgcn_s_barrier();
    COMPUTE(cur, afrag);

    // --- write partials: D row = lgrp*4 + r, col = fr (m89-verified mapping) ---
    float* pout = partial + (size_t)s * (M_TOT * F_TOT);
#pragma unroll
    for (int mt = 0; mt < 8; ++mt) {
        int mbase = mt * 16 + lgrp * 4;
#pragma unroll
        for (int ft = 0; ft < 2; ++ft) {
            int f = f0 + wave * 32 + ft * 16 + fr;
#pragma unroll
            for (int r = 0; r < 4; ++r)
                pout[(size_t)(mbase + r) * F_TOT + f] = acc[mt][ft][r];
        }
    }
}

// ---------------- kernel 3: split-K reduce + bias (vectorized) ----------------
__global__ void reduce_kernel(const float* __restrict__ partial,
                              const float* __restrict__ bias,
                              float* __restrict__ out, int S) {
    int i4 = (blockIdx.x * blockDim.x + threadIdx.x) * 4;
    if (i4 >= M_TOT * F_TOT) return;
    f32x4 a = *reinterpret_cast<const f32x4*>(bias + (i4 & (F_TOT - 1)));
    for (int s = 0; s < S; ++s)
        a += *reinterpret_cast<const f32x4*>(partial + (size_t)s * (M_TOT * F_TOT) + i4);
    *reinterpret_cast<f32x4*>(out + i4) = a;
}

extern "C" void kernel_launch(void* const* d_in, const int* in_sizes, int n_in,
                              void* d_out, int out_size, void* d_ws, size_t ws_size,
                              hipStream_t stream) {
    const float* x    = (const float*)d_in[0];
    const int*   cent = (const int*)d_in[1];
    const float* W    = (const float*)d_in[2];
    const float* bias = (const float*)d_in[3];
    float* out = (float*)d_out;

    unsigned short* Af = (unsigned short*)d_ws;
    size_t Af_bytes = (size_t)KSTEPS * 4096 * 2;                 // 27,648,000
    float* partial = (float*)((char*)d_ws + Af_bytes);

    size_t avail = ws_size > Af_bytes ? ws_size - Af_bytes : 0;
    int S = (int)(avail / ((size_t)M_TOT * F_TOT * 4));
    if (S > 64) S = 64;                   // target: grid 8x64 = 512 = 2/CU
    if (S < 1)  S = 1;
    int CS = (KSTEPS + S - 1) / S;        // 53 for S=64
    S = (KSTEPS + CS - 1) / CS;           // 64 (last chunk = 36 steps)

    extract_kernel<<<dim3(M_TOT, C_), 256, 0, stream>>>(x, cent, Af);
    gemm_kernel<<<dim3(8, S), 256, 0, stream>>>(Af, W, partial, CS);
    reduce_kernel<<<dim3((M_TOT * F_TOT + 1023) / 1024, 1, 1), 256, 0, stream>>>(partial, bias, out, S);
}